// Round 3
// baseline (26.961 us; speedup 1.0000x reference)
//
#include <hip/hip_runtime.h>
#include <math.h>

// Problem constants: B=32, H=100, C=50, D=400, HID=400
#define B_   32
#define H_   100
#define C_   50
#define D_   400
#define HID_ 400
#define NTILES 7   // ceil(D/64) output d-tiles per b

#define NEGF (-3.4028234663852886e38f)  // finfo(float32).min

// Algebraic collapse (verified R1/R2, absmax 1.5e-5):
//   softmax over h cancels the cand/bias terms; weights[b,h] =
//   softmax_h(mask ? hist[b,h]·u : finfo.min), u = W1[D:,:] @ w2.
//   out[b,c,:] = mask_cand[b,c] ? sum_h w[b,h]*hist[b,h,:] : 0
//
// R2: 3 dispatches, 17 us — dominated by dispatch gaps. This round: 2
// dispatches. K2 fuses score+softmax+output; each block redundantly computes
// s[b,:] (reads hist[b], 160 KB); XCD-aware mapping keeps the 7 blocks of a
// given b on one XCD so the redundant reads are L2 hits, not HBM.

// ---- K1: u[row] = dot(W1[D+row,:], w2). One wave/row, float4. grid=50x512 ----
__global__ __launch_bounds__(512)
void k1_u(const float* __restrict__ W1, const float* __restrict__ w2,
          float* __restrict__ u) {
    const int row  = blockIdx.x * 8 + (threadIdx.x >> 6);   // 0..399
    const int lane = threadIdx.x & 63;
    const float4* r4 = (const float4*)(W1 + (size_t)(D_ + row) * HID_);
    const float4* w4 = (const float4*)w2;
    float4 a0 = r4[lane];
    float4 b0 = w4[lane];
    float acc = a0.x*b0.x + a0.y*b0.y + a0.z*b0.z + a0.w*b0.w;
    if (lane < 36) {   // 100 float4 per row: 64 + 36
        float4 a1 = r4[64 + lane];
        float4 b1 = w4[64 + lane];
        acc += a1.x*b1.x + a1.y*b1.y + a1.z*b1.z + a1.w*b1.w;
    }
    #pragma unroll
    for (int off = 32; off; off >>= 1) acc += __shfl_xor(acc, off, 64);
    if (lane == 0) u[row] = acc;
}

// ---- K2: fused scores + softmax + weighted sum + masked broadcast store.
//      grid = 224 (32 b x 7 tiles, XCD-aware), block = 256 ----
__global__ __launch_bounds__(256)
void k2_fused(const float* __restrict__ hist, const float* __restrict__ u,
              const int* __restrict__ mask_hist, const int* __restrict__ mask_cand,
              float* __restrict__ out) {
    __shared__ float s_lds[H_];
    __shared__ float w_lds[H_];
    __shared__ float part[4][64];

    // XCD-aware decode: assume xcd = blockIdx % 8 (round-robin). All 7 tiles
    // of a b share a residue class -> hist[b] fetched from HBM once per XCD.
    const int x    = blockIdx.x & 7;
    const int k    = blockIdx.x >> 3;        // 0..27
    const int q    = k / 7;                  // 0..3
    const int b    = x + 8 * q;              // 0..31
    const int tile = k - 7 * q;              // 0..6
    const int d0   = tile * 64;
    const int lane = threadIdx.x & 63;
    const int wave = threadIdx.x >> 6;

    const float* hb = hist + (size_t)b * H_ * D_;

    // u in registers per lane (100 float4 = 64 + 36)
    const float4* u4 = (const float4*)u;
    float4 ua = u4[lane];
    float4 ub = (lane < 36) ? u4[64 + lane] : make_float4(0.f, 0.f, 0.f, 0.f);

    // --- Phase 1: s[h] = mask ? hist[b,h]·u : NEG ; wave w owns 25 rows ---
    const int* mh = mask_hist + b * H_;
    for (int i = 0; i < 25; i++) {
        const int h = wave * 25 + i;
        const float4* r4 = (const float4*)(hb + (size_t)h * D_);
        float4 a = r4[lane];
        float acc = a.x*ua.x + a.y*ua.y + a.z*ua.z + a.w*ua.w;
        if (lane < 36) {
            float4 a1 = r4[64 + lane];
            acc += a1.x*ub.x + a1.y*ub.y + a1.z*ub.z + a1.w*ub.w;
        }
        #pragma unroll
        for (int off = 32; off; off >>= 1) acc += __shfl_xor(acc, off, 64);
        if (lane == 0) s_lds[h] = mh[h] ? acc : NEGF;
    }
    __syncthreads();

    // --- Phase 2: softmax over s_lds[0..99], redundant per wave ---
    const float s0 = s_lds[lane];
    const float s1 = (lane < 36) ? s_lds[lane + 64] : -INFINITY;
    float m = fmaxf(s0, s1);
    #pragma unroll
    for (int off = 32; off; off >>= 1) m = fmaxf(m, __shfl_xor(m, off, 64));
    const float e0 = expf(s0 - m);
    const float e1 = (lane < 36) ? expf(s1 - m) : 0.f;
    float ps = e0 + e1;
    #pragma unroll
    for (int off = 32; off; off >>= 1) ps += __shfl_xor(ps, off, 64);
    const float inv = 1.f / ps;
    if (wave == 0) {
        w_lds[lane] = e0 * inv;
        if (lane < 36) w_lds[lane + 64] = e1 * inv;
    }
    __syncthreads();

    // --- Phase 3: uv[d0+lane] partials, wave w owns h in [25w, 25w+25) ---
    const int d = d0 + lane;                 // may be >= 400 on tile 6
    float acc = 0.f;
    if (d < D_) {
        const int h0 = wave * 25;
        #pragma unroll
        for (int i = 0; i < 25; i++)
            acc = fmaf(w_lds[h0 + i], hb[(size_t)(h0 + i) * D_ + d], acc);
    }
    part[wave][lane] = acc;
    __syncthreads();

    // --- Phase 4: reduce + masked broadcast store of 50 c's ---
    const float uv = part[0][lane] + part[1][lane] + part[2][lane] + part[3][lane];
    const int* mc  = mask_cand + b * C_;
    float* outb = out + (size_t)b * C_ * D_ + d0;
    if (d < D_) {
        for (int c = wave; c < C_; c += 4)
            outb[(size_t)c * D_ + lane] = mc[c] ? uv : 0.f;
    }
}

extern "C" void kernel_launch(void* const* d_in, const int* in_sizes, int n_in,
                              void* d_out, int out_size, void* d_ws, size_t ws_size,
                              hipStream_t stream) {
    // inputs: 0 hist(B,H,D) f32, 1 cand [unused], 2 mask_hist(B,H) i32,
    //         3 mask_cand(B,C) i32, 4 W1(2D,HID) f32, 5 b1 [unused],
    //         6 w2(HID) f32, 7 b2 [unused]
    const float* hist      = (const float*)d_in[0];
    const int*   mask_hist = (const int*)d_in[2];
    const int*   mask_cand = (const int*)d_in[3];
    const float* W1        = (const float*)d_in[4];
    const float* w2        = (const float*)d_in[6];
    float* out = (float*)d_out;

    float* u = (float*)d_ws;   // 400 floats of scratch

    k1_u    <<<D_ / 8,      512, 0, stream>>>(W1, w2, u);
    k2_fused<<<B_ * NTILES, 256, 0, stream>>>(hist, u, mask_hist, mask_cand, out);
}